// Round 14
// baseline (220.692 us; speedup 1.0000x reference)
//
#include <hip/hip_runtime.h>

#define BB 2
#define SS 2048
#define DD 1024
#define HH 16
#define DEPTH 64
#define MTOT (BB*SS)   // 4096
#define QW 8           // waves per attn block
#define QBLK (QW*16)   // 128 q-rows per block
#define NT (SS/64)     // 32 k-tiles (pass 2)
#define NT2 (SS/128)   // 16 double-width k-tiles (pass 1)
#define NPROJ ((size_t)BB*HH*SS*DEPTH)   // 4,194,304 elems
#define WSZ   ((size_t)DD*DD)            // 1,048,576 elems

using f16 = _Float16;
typedef _Float16 f16x8 __attribute__((ext_vector_type(8)));
typedef _Float16 f16x4 __attribute__((ext_vector_type(4)));
typedef float f32x4 __attribute__((ext_vector_type(4)));

#define LOG2E 1.44269504088896f
#define SC2   (0.125f * LOG2E)    // logit scale folded with log2e for v_exp_f32

// HBM->LDS direct copy, 16B per lane. LDS dest is wave-uniform base + lane*16.
#define GLOAD16(g, l) __builtin_amdgcn_global_load_lds(                      \
    (__attribute__((address_space(1))) const void*)(g),                      \
    (__attribute__((address_space(3))) void*)(l), 16, 0, 0)

// Counted-vmcnt barrier (T4): drain only the oldest VMEM ops (the gloads for
// the tile read NEXT iter); newer prefetch + NT-store acks stay in flight.
#define BARV(N) do {                                                         \
    __builtin_amdgcn_sched_barrier(0);                                       \
    asm volatile("s_waitcnt vmcnt(" #N ") lgkmcnt(0)" ::: "memory");         \
    __builtin_amdgcn_sched_barrier(0);                                       \
    __builtin_amdgcn_s_barrier();                                            \
    __builtin_amdgcn_sched_barrier(0);                                       \
} while (0)

// End-of-kernel safety: outstanding global_load_lds must complete before the
// workgroup's LDS can be reallocated.
#define ENDDRAIN() asm volatile("s_waitcnt vmcnt(0)" ::: "memory")

// ---------------- fp32 -> f16 convert (q,k,v, wq,wk,wv) ----------------
__global__ __launch_bounds__(256) void cvt_kernel(
    const float* __restrict__ q, const float* __restrict__ k, const float* __restrict__ v,
    const float* __restrict__ w0, const float* __restrict__ w1, const float* __restrict__ w2,
    f16* __restrict__ qf, f16* __restrict__ kf, f16* __restrict__ vf,
    f16* __restrict__ wq, f16* __restrict__ wk, f16* __restrict__ wv)
{
    const int z = blockIdx.y;
    const float* s = z==0?q : z==1?k : z==2?v : z==3?w0 : z==4?w1 : w2;
    f16*        d = z==0?qf: z==1?kf: z==2?vf: z==3?wq: z==4?wk: wv;
    const size_t n = (z < 3) ? NPROJ : WSZ;
    for (size_t i = ((size_t)blockIdx.x * 256 + threadIdx.x) * 8; i < n;
         i += (size_t)gridDim.x * 256 * 8) {
        f32x4 a = *(const f32x4*)(s + i);
        f32x4 b = *(const f32x4*)(s + i + 4);
        f16x8 o = {(f16)a[0], (f16)a[1], (f16)a[2], (f16)a[3],
                   (f16)b[0], (f16)b[1], (f16)b[2], (f16)b[3]};
        *(f16x8*)(d + i) = o;
    }
}

// ---------------- single-array fp32 -> f16 (dense_w, post-attn) ----------------
__global__ __launch_bounds__(256) void cvt2_kernel(
    const float* __restrict__ s, f16* __restrict__ d)
{
    size_t i = ((size_t)blockIdx.x * 256 + threadIdx.x) * 8;
    if (i < WSZ) {
        f32x4 a = *(const f32x4*)(s + i);
        f32x4 b = *(const f32x4*)(s + i + 4);
        f16x8 o = {(f16)a[0], (f16)a[1], (f16)a[2], (f16)a[3],
                   (f16)b[0], (f16)b[1], (f16)b[2], (f16)b[3]};
        *(f16x8*)(d + i) = o;
    }
}

// ---------------- Projection GEMM (f16): out = X @ W^T + b ----------------
// 3-buffer BK=32, 2-deep prefetch, counted-vmcnt BARV(4) (r13-validated
// structure ported from attn). 48KB LDS -> 3 blocks/CU = grid residency.
// mode 0: Q -> qh [b,h,s,d]   mode 1: K -> kh [b,h,s,d]   mode 2: V -> vt [b,h,d,s]
__global__ __launch_bounds__(256, 3) void proj_kernel(
    const f16* __restrict__ qf, const f16* __restrict__ kf, const f16* __restrict__ vf,
    const f16* __restrict__ wqw, const f16* __restrict__ wkw, const f16* __restrict__ wvw,
    const float* __restrict__ bq, const float* __restrict__ bk, const float* __restrict__ bv,
    f16* __restrict__ qh, f16* __restrict__ kh, f16* __restrict__ vt)
{
    const int mode = blockIdx.z;
    const f16* A    = mode==0 ? qf  : mode==1 ? kf  : vf;
    const f16* Bw   = mode==0 ? wqw : mode==1 ? wkw : wvw;
    const float* bias = mode==0 ? bq : mode==1 ? bk : bv;

    __shared__ f16 As[3][128*32];   // 8KB/buf, linear dest, swizzled content
    __shared__ f16 Bs[3][128*32];

    const int tid = threadIdx.x, wave = tid >> 6, lane = tid & 63;
    const int m0 = blockIdx.y * 128, n0 = blockIdx.x * 128;
    const int wm = (wave >> 1) * 64, wn = (wave & 1) * 64;
    const int lrow = lane & 15, g = lane >> 4;
    // rows are 64B (half the banks): rows r,r+2 alias. XOR chunk by (r>>1)&3
    // spreads each parity-class over all 4 chunk slots -> 2-way max (free).
    const int rchk = (lrow >> 1) & 3;             // read-side chunk XOR
    const int srow = tid >> 2;                    // row within 64-row sweep
    const int schk = (tid & 3) ^ ((tid >> 3) & 3);// inverse-swizzled source chunk

    f32x4 acc[4][4] = {};

    auto stage = [&](int t, int buf) {
        const int kk = t * 32;
        #pragma unroll
        for (int s2 = 0; s2 < 2; ++s2) {
            GLOAD16(A  + (size_t)(m0 + s2*64 + srow) * DD + kk + schk * 8,
                    &As[buf][s2*2048 + wave*512]);
            GLOAD16(Bw + (size_t)(n0 + s2*64 + srow) * DD + kk + schk * 8,
                    &Bs[buf][s2*2048 + wave*512]);
        }
    };

    stage(0, 0);
    stage(1, 1);
    BARV(4);                                   // drain t=0's gloads; t=1 in flight
    for (int t = 0; t < DD/32; ++t) {
        const int cur = t % 3;
        const int nxt = (t + 2) % 3;
        const int t2 = (t + 2) & (DD/32 - 1);  // wraparound keeps FIFO uniform
        stage(t2, nxt);
        f16x8 a[4], bf[4];
        #pragma unroll
        for (int i = 0; i < 4; ++i)
            a[i]  = *(const f16x8*)&As[cur][(wm + i*16 + lrow)*32 + (g ^ rchk)*8];
        #pragma unroll
        for (int i = 0; i < 4; ++i)
            bf[i] = *(const f16x8*)&Bs[cur][(wn + i*16 + lrow)*32 + (g ^ rchk)*8];
        for (int mi = 0; mi < 4; ++mi)
            for (int ni = 0; ni < 4; ++ni)
                acc[mi][ni] = __builtin_amdgcn_mfma_f32_16x16x32_f16(a[mi], bf[ni], acc[mi][ni], 0, 0, 0);
        BARV(4);                               // drains gloads(t+1); gloads(t+2) stay
    }
    ENDDRAIN();                                // wraparound gloads before LDS dealloc

    const int rbase = g * 4;
    if (mode == 2) {
        for (int ni = 0; ni < 4; ++ni) {
            int n = n0 + wn + ni * 16 + lrow;
            float bval = bias[n];
            int hh = n >> 6, dep = n & 63;
            for (int mi = 0; mi < 4; ++mi) {
                int m = m0 + wm + mi * 16 + rbase;
                int bb = m >> 11, s = m & 2047;
                f16x4 pk = {(f16)(acc[mi][ni][0] + bval), (f16)(acc[mi][ni][1] + bval),
                            (f16)(acc[mi][ni][2] + bval), (f16)(acc[mi][ni][3] + bval)};
                *(f16x4*)&vt[((size_t)(bb * HH + hh) * DEPTH + dep) * SS + s] = pk;
            }
        }
    } else {
        f16* dst = (mode == 0) ? qh : kh;
        for (int ni = 0; ni < 4; ++ni) {
            int n = n0 + wn + ni * 16 + lrow;
            float bval = bias[n];
            int hh = n >> 6, dep = n & 63;
            for (int mi = 0; mi < 4; ++mi)
                for (int j = 0; j < 4; ++j) {
                    int m = m0 + wm + mi * 16 + rbase + j;
                    int bb = m >> 11, s = m & 2047;
                    dst[((size_t)(bb * HH + hh) * SS + s) * DEPTH + dep] = (f16)(acc[mi][ni][j] + bval);
                }
        }
    }
}

// ---------------- Attention (round-13 verified form + end drain) ----------------
__global__ __launch_bounds__(512, 4) void attn_kernel(
    const f16* __restrict__ qh, const f16* __restrict__ kh, const f16* __restrict__ vt,
    const float* __restrict__ mask, float* __restrict__ attn_out, f16* __restrict__ ctx)
{
    __shared__ unsigned char mflag[SS];   // key-padding flags, 2KB
    __shared__ f16 Ks[3][64*64];          // K 3-buf (pass1: first 64 rows of 128-tile)
    __shared__ f16 Vs[3][64*64];          // V 3-buf (pass1: rows 64-127 of K-tile)
    __shared__ f16 Pl[QW][16][72];        // per-wave P bounce, 18KB

    const int tid = threadIdx.x, wave = tid >> 6, lane = tid & 63;
    const int L = blockIdx.x;             // 0..511; L&7 = XCD
    const int xcd = L & 7, iw = L >> 3;
    const int bh = xcd * 4 + (iw >> 4);   // 4 bh per XCD -> 2MB K/V per L2
    const int qb = iw & 15;
    const int b = bh >> 4, h = bh & 15;
    const int q0 = qb * QBLK;
    const int lrow = lane & 15, g = lane >> 4;
    const int rbase = g * 4;
    const int sw = lrow & 7;
    const int srow = tid >> 3;
    const int schk = (tid & 7) ^ (srow & 7);

    const f16* Qbase = qh + (size_t)bh * SS * DEPTH;
    const f16* Kb = kh + (size_t)bh * SS * DEPTH;
    const f16* Vb = vt + (size_t)bh * DEPTH * SS;

    for (int i = tid; i < SS; i += 512)
        mflag[i] = mask[b * SS + i] > 0.5f ? 1 : 0;

    f16x8 aq[2];
    for (int kf2 = 0; kf2 < 2; ++kf2)
        aq[kf2] = *(const f16x8*)(Qbase + (size_t)(q0 + wave*16 + lrow) * DEPTH + kf2*32 + g*8);

    // ---- pass 1: row sums of sel*exp2(logit), 128-row K tiles, 2-deep prefetch ----
    float s_l[4] = {0.f, 0.f, 0.f, 0.f};
    GLOAD16(Kb + (size_t)(srow) * DEPTH + schk * 8,        &Ks[0][wave * 512]);
    GLOAD16(Kb + (size_t)(64 + srow) * DEPTH + schk * 8,   &Vs[0][wave * 512]);
    GLOAD16(Kb + (size_t)(128 + srow) * DEPTH + schk * 8,  &Ks[1][wave * 512]);
    GLOAD16(Kb + (size_t)(192 + srow) * DEPTH + schk * 8,  &Vs[1][wave * 512]);
    __syncthreads();
    for (int t = 0; t < NT2; ++t) {
        const int cur = t % 3;
        const int nxt = (t + 2) % 3;
        const int t2 = (t + 2) & (NT2 - 1);   // wraparound keeps FIFO uniform
        GLOAD16(Kb + (size_t)(t2*128 + srow) * DEPTH + schk * 8,      &Ks[nxt][wave * 512]);
        GLOAD16(Kb + (size_t)(t2*128 + 64 + srow) * DEPTH + schk * 8, &Vs[nxt][wave * 512]);
        #pragma unroll
        for (int nf = 0; nf < 8; ++nf) {
            const f16* tb = (nf < 4) ? &Ks[cur][0] : &Vs[cur][0];
            const int nfl = nf & 3;
            f32x4 a4 = {};
            for (int kf2 = 0; kf2 < 2; ++kf2) {
                f16x8 bf = *(const f16x8*)&tb[(nfl*16 + lrow)*64 + ((kf2*4 + g) ^ sw)*8];
                a4 = __builtin_amdgcn_mfma_f32_16x16x32_f16(aq[kf2], bf, a4, 0, 0, 0);
            }
            float sel = mflag[t*128 + nf*16 + lrow] ? 0.f : 1.f;
            for (int j = 0; j < 4; ++j)
                s_l[j] += sel * __builtin_amdgcn_exp2f(a4[j] * SC2);
        }
        if (t < NT2 - 1) BARV(2);
        else __syncthreads();   // full drain: stale wraparound gloads must not race pass-2 prologue
    }
    for (int j = 0; j < 4; ++j) {
        float s = s_l[j];
        for (int off = 1; off < 16; off <<= 1) s += __shfl_xor(s, off);
        s_l[j] = 1.0f / s;
    }

    // ---- pass 2: 2-deep prefetch, vmcnt(6) barriers, deferred NT stores ----
    f32x4 cacc[4] = {};
    f32x4 st[4];                           // deferred attn store regs (tile kt-1)
    float* arow = attn_out + ((size_t)bh * SS + q0 + wave * 16) * SS;
    GLOAD16(Kb + (size_t)(srow) * DEPTH + schk * 8,        &Ks[0][wave * 512]);
    GLOAD16(Vb + (size_t)srow * SS + 0 + schk * 8,         &Vs[0][wave * 512]);
    GLOAD16(Kb + (size_t)(64 + srow) * DEPTH + schk * 8,   &Ks[1][wave * 512]);
    GLOAD16(Vb + (size_t)srow * SS + 64 + schk * 8,        &Vs[1][wave * 512]);
    __syncthreads();
    for (int kt = 0; kt < NT; ++kt) {
        const int cur = kt % 3;
        const int nxt = (kt + 2) % 3;
        const int t2 = (kt + 2) & (NT - 1);
        // previous tile's stores first (a full iteration of ack slack before any drain)
        if (kt > 0) {
            #pragma unroll
            for (int i = 0; i < 4; ++i) {
                int r = i * 4 + g;
                __builtin_nontemporal_store(st[i],
                    (f32x4*)&arow[(size_t)r * SS + (kt-1)*64 + lrow*4]);
            }
        }
        GLOAD16(Kb + (size_t)(t2*64 + srow) * DEPTH + schk * 8, &Ks[nxt][wave * 512]);
        GLOAD16(Vb + (size_t)srow * SS + t2*64 + schk * 8,      &Vs[nxt][wave * 512]);
        // QK^T + normalized P -> Pl
        for (int nf = 0; nf < 4; ++nf) {
            f32x4 a4 = {};
            for (int kf2 = 0; kf2 < 2; ++kf2) {
                f16x8 bf = *(const f16x8*)&Ks[cur][(nf*16 + lrow)*64 + ((kf2*4 + g) ^ sw)*8];
                a4 = __builtin_amdgcn_mfma_f32_16x16x32_f16(aq[kf2], bf, a4, 0, 0, 0);
            }
            float sel = mflag[kt*64 + nf*16 + lrow] ? 0.f : 1.f;
            for (int j = 0; j < 4; ++j) {
                float p = sel * __builtin_amdgcn_exp2f(a4[j] * SC2) * s_l[j];
                Pl[wave][rbase + j][nf*16 + lrow] = (f16)p;
            }
        }
        // PV: A = P (same-wave LDS bounce), B = V tile
        for (int kf2 = 0; kf2 < 2; ++kf2) {
            f16x8 pa = *(const f16x8*)&Pl[wave][lrow][kf2*32 + g*8];
            for (int nf = 0; nf < 4; ++nf) {
                f16x8 bv = *(const f16x8*)&Vs[cur][(nf*16 + lrow)*64 + ((kf2*4 + g) ^ sw)*8];
                cacc[nf] = __builtin_amdgcn_mfma_f32_16x16x32_f16(pa, bv, cacc[nf], 0, 0, 0);
            }
        }
        // read this tile's attn rows (transposed) into regs for deferred store
        #pragma unroll
        for (int i = 0; i < 4; ++i) {
            int r = i * 4 + g;
            f16x4 pv4 = *(const f16x4*)&Pl[wave][r][lrow * 4];
            st[i] = (f32x4){(float)pv4[0], (float)pv4[1], (float)pv4[2], (float)pv4[3]};
        }
        BARV(6);   // drains gloads(kt+1) exactly; stores(kt-1)+gloads(kt+2) stay in flight
    }
    // final tile's stores
    #pragma unroll
    for (int i = 0; i < 4; ++i) {
        int r = i * 4 + g;
        __builtin_nontemporal_store(st[i],
            (f32x4*)&arow[(size_t)r * SS + (NT-1)*64 + lrow*4]);
    }
    // ctx [b, s, h, d] f16 for dense GEMM
    for (int nf = 0; nf < 4; ++nf)
        for (int j = 0; j < 4; ++j) {
            int qrow = q0 + wave * 16 + rbase + j;
            ctx[((size_t)(b * SS + qrow) * HH + h) * DEPTH + nf*16 + lrow] = (f16)cacc[nf][j];
        }
    ENDDRAIN();   // wraparound gloads must land before LDS is reallocated
}

// ---------------- Dense (f16 A/B, round-12 verified form) ----------------
__global__ __launch_bounds__(256, 4) void dense_kernel(
    const f16* __restrict__ ctx, const f16* __restrict__ W16,
    const float* __restrict__ bias, float* __restrict__ out)
{
    __shared__ f16 As[128*64];
    __shared__ f16 Bs[128*64];

    const int tid = threadIdx.x, wave = tid >> 6, lane = tid & 63;
    const int m0 = blockIdx.y * 128, n0 = blockIdx.x * 128;
    const int wm = (wave >> 1) * 64, wn = (wave & 1) * 64;
    const int lrow = lane & 15, g = lane >> 4;
    const int sw = lrow & 7;
    const int srow = tid >> 3;
    const int schk = (tid & 7) ^ (srow & 7);

    f32x4 acc[4][4] = {};

    for (int kk = 0; kk < DD; kk += 64) {
        #pragma unroll
        for (int i = 0; i < 4; ++i) {
            GLOAD16(ctx + (size_t)(m0 + i*32 + srow) * DD + kk + schk * 8,
                    &As[i*2048 + wave*512]);
            GLOAD16(W16 + (size_t)(n0 + i*32 + srow) * DD + kk + schk * 8,
                    &Bs[i*2048 + wave*512]);
        }
        __syncthreads();
        for (int kf2 = 0; kf2 < 2; ++kf2) {
            f16x8 a[4], bf[4];
            for (int i = 0; i < 4; ++i)
                a[i]  = *(const f16x8*)&As[(wm + i*16 + lrow)*64 + ((kf2*4 + g) ^ sw)*8];
            for (int i = 0; i < 4; ++i)
                bf[i] = *(const f16x8*)&Bs[(wn + i*16 + lrow)*64 + ((kf2*4 + g) ^ sw)*8];
            for (int mi = 0; mi < 4; ++mi)
                for (int ni = 0; ni < 4; ++ni)
                    acc[mi][ni] = __builtin_amdgcn_mfma_f32_16x16x32_f16(a[mi], bf[ni], acc[mi][ni], 0, 0, 0);
        }
        __syncthreads();
    }

    const int rbase = g * 4;
    for (int ni = 0; ni < 4; ++ni) {
        int n = n0 + wn + ni * 16 + lrow;
        float bval = bias[n];
        for (int mi = 0; mi < 4; ++mi)
            for (int j = 0; j < 4; ++j) {
                int m = m0 + wm + mi * 16 + rbase + j;
                out[(size_t)m * DD + n] = acc[mi][ni][j] + bval;
            }
    }
}

extern "C" void kernel_launch(void* const* d_in, const int* in_sizes, int n_in,
                              void* d_out, int out_size, void* d_ws, size_t ws_size,
                              hipStream_t stream) {
    const float* q       = (const float*)d_in[0];
    const float* k       = (const float*)d_in[1];
    const float* v       = (const float*)d_in[2];
    const float* mask    = (const float*)d_in[3];
    const float* wq_w    = (const float*)d_in[4];
    const float* wq_b    = (const float*)d_in[5];
    const float* wk_w    = (const float*)d_in[6];
    const float* wk_b    = (const float*)d_in[7];
    const float* wv_w    = (const float*)d_in[8];
    const float* wv_b    = (const float*)d_in[9];
    const float* dense_w = (const float*)d_in[10];
    const float* dense_b = (const float*)d_in[11];

    float* out  = (float*)d_out;
    float* attn = out + (size_t)MTOT * DD;          // output-1 region (537MB)

    // ws: persistent intermediates (proven <= ws_size: 33.6MB)
    f16* qh  = (f16*)d_ws;
    f16* kh  = qh + NPROJ;
    f16* vt  = kh + NPROJ;
    f16* ctx = vt + NPROJ;

    // Transient f16 copies in the attn OUTPUT region (dead after proj; attn
    // pass 2 overwrites the whole region afterwards, stream-ordered).
    f16* sc   = (f16*)attn;
    f16* qf   = sc;
    f16* kf   = sc + NPROJ;
    f16* vf   = sc + 2*NPROJ;
    f16* wq16 = sc + 3*NPROJ;
    f16* wk16 = wq16 + WSZ;
    f16* wv16 = wk16 + WSZ;

    // dense_w f16 copy lives in the qh region (dead after attn completes).
    f16* dw16 = qh;

    cvt_kernel<<<dim3(1024, 6), 256, 0, stream>>>(q, k, v, wq_w, wk_w, wv_w,
                                                  qf, kf, vf, wq16, wk16, wv16);
    proj_kernel<<<dim3(8, 32, 3), 256, 0, stream>>>(qf, kf, vf, wq16, wk16, wv16,
                                                    wq_b, wk_b, wv_b, qh, kh, vt);
    attn_kernel<<<dim3(512), 512, 0, stream>>>(qh, kh, vt, mask, attn, ctx);
    cvt2_kernel<<<dim3(512), 256, 0, stream>>>(dense_w, dw16);
    dense_kernel<<<dim3(8, 32), 256, 0, stream>>>(ctx, dw16, dense_b, out);
}

// Round 15
// 216.631 us; speedup vs baseline: 1.0187x; 1.0187x over previous
//
#include <hip/hip_runtime.h>

#define BB 2
#define SS 2048
#define DD 1024
#define HH 16
#define DEPTH 64
#define MTOT (BB*SS)   // 4096
#define QW 8           // waves per attn block
#define QBLK (QW*16)   // 128 q-rows per block
#define NT (SS/64)     // 32 k-tiles (pass 2)
#define NT2 (SS/128)   // 16 double-width k-tiles (pass 1)
#define NPROJ ((size_t)BB*HH*SS*DEPTH)   // 4,194,304 elems
#define WSZ   ((size_t)DD*DD)            // 1,048,576 elems

using f16 = _Float16;
typedef _Float16 f16x8 __attribute__((ext_vector_type(8)));
typedef _Float16 f16x4 __attribute__((ext_vector_type(4)));
typedef float f32x4 __attribute__((ext_vector_type(4)));

#define LOG2E 1.44269504088896f
#define SC2   (0.125f * LOG2E)    // folded into qh at proj mode-0 epilogue

// HBM->LDS direct copy, 16B per lane. LDS dest is wave-uniform base + lane*16.
#define GLOAD16(g, l) __builtin_amdgcn_global_load_lds(                      \
    (__attribute__((address_space(1))) const void*)(g),                      \
    (__attribute__((address_space(3))) void*)(l), 16, 0, 0)

// Counted-vmcnt barrier (T4): drain only the oldest VMEM ops.
#define BARV(N) do {                                                         \
    __builtin_amdgcn_sched_barrier(0);                                       \
    asm volatile("s_waitcnt vmcnt(" #N ") lgkmcnt(0)" ::: "memory");         \
    __builtin_amdgcn_sched_barrier(0);                                       \
    __builtin_amdgcn_s_barrier();                                            \
    __builtin_amdgcn_sched_barrier(0);                                       \
} while (0)

// End-of-kernel safety: outstanding global_load_lds must complete before the
// workgroup's LDS can be reallocated.
#define ENDDRAIN() asm volatile("s_waitcnt vmcnt(0)" ::: "memory")

// ---------------- fp32 -> f16 convert (q,k,v, wq,wk,wv) ----------------
__global__ __launch_bounds__(256) void cvt_kernel(
    const float* __restrict__ q, const float* __restrict__ k, const float* __restrict__ v,
    const float* __restrict__ w0, const float* __restrict__ w1, const float* __restrict__ w2,
    f16* __restrict__ qf, f16* __restrict__ kf, f16* __restrict__ vf,
    f16* __restrict__ wq, f16* __restrict__ wk, f16* __restrict__ wv)
{
    const int z = blockIdx.y;
    const float* s = z==0?q : z==1?k : z==2?v : z==3?w0 : z==4?w1 : w2;
    f16*        d = z==0?qf: z==1?kf: z==2?vf: z==3?wq: z==4?wk: wv;
    const size_t n = (z < 3) ? NPROJ : WSZ;
    for (size_t i = ((size_t)blockIdx.x * 256 + threadIdx.x) * 8; i < n;
         i += (size_t)gridDim.x * 256 * 8) {
        f32x4 a = *(const f32x4*)(s + i);
        f32x4 b = *(const f32x4*)(s + i + 4);
        f16x8 o = {(f16)a[0], (f16)a[1], (f16)a[2], (f16)a[3],
                   (f16)b[0], (f16)b[1], (f16)b[2], (f16)b[3]};
        *(f16x8*)(d + i) = o;
    }
}

// ---------------- single-array fp32 -> f16 (dense_w, post-attn) ----------------
__global__ __launch_bounds__(256) void cvt2_kernel(
    const float* __restrict__ s, f16* __restrict__ d)
{
    size_t i = ((size_t)blockIdx.x * 256 + threadIdx.x) * 8;
    if (i < WSZ) {
        f32x4 a = *(const f32x4*)(s + i);
        f32x4 b = *(const f32x4*)(s + i + 4);
        f16x8 o = {(f16)a[0], (f16)a[1], (f16)a[2], (f16)a[3],
                   (f16)b[0], (f16)b[1], (f16)b[2], (f16)b[3]};
        *(f16x8*)(d + i) = o;
    }
}

// ---------------- Projection GEMM (f16, r13 verified form) ----------------
// mode 0: Q -> qh [b,h,s,d] scaled by SC2   mode 1: K -> kh   mode 2: V -> vt [b,h,d,s]
__global__ __launch_bounds__(256, 4) void proj_kernel(
    const f16* __restrict__ qf, const f16* __restrict__ kf, const f16* __restrict__ vf,
    const f16* __restrict__ wqw, const f16* __restrict__ wkw, const f16* __restrict__ wvw,
    const float* __restrict__ bq, const float* __restrict__ bk, const float* __restrict__ bv,
    f16* __restrict__ qh, f16* __restrict__ kh, f16* __restrict__ vt)
{
    const int mode = blockIdx.z;
    const f16* A    = mode==0 ? qf  : mode==1 ? kf  : vf;
    const f16* Bw   = mode==0 ? wqw : mode==1 ? wkw : wvw;
    const float* bias = mode==0 ? bq : mode==1 ? bk : bv;

    __shared__ f16 As[128*64];   // linear (gload_lds dest), chunk-swizzled content
    __shared__ f16 Bs[128*64];

    const int tid = threadIdx.x, wave = tid >> 6, lane = tid & 63;
    const int m0 = blockIdx.y * 128, n0 = blockIdx.x * 128;
    const int wm = (wave >> 1) * 64, wn = (wave & 1) * 64;
    const int lrow = lane & 15, g = lane >> 4;
    const int sw = lrow & 7;
    const int srow = tid >> 3;
    const int schk = (tid & 7) ^ (srow & 7);

    f32x4 acc[4][4] = {};

    for (int kk = 0; kk < DD; kk += 64) {
        #pragma unroll
        for (int i = 0; i < 4; ++i) {
            GLOAD16(A  + (size_t)(m0 + i*32 + srow) * DD + kk + schk * 8,
                    &As[i*2048 + wave*512]);
            GLOAD16(Bw + (size_t)(n0 + i*32 + srow) * DD + kk + schk * 8,
                    &Bs[i*2048 + wave*512]);
        }
        __syncthreads();
        for (int kf2 = 0; kf2 < 2; ++kf2) {
            f16x8 a[4], bf[4];
            for (int i = 0; i < 4; ++i)
                a[i]  = *(const f16x8*)&As[(wm + i*16 + lrow)*64 + ((kf2*4 + g) ^ sw)*8];
            for (int i = 0; i < 4; ++i)
                bf[i] = *(const f16x8*)&Bs[(wn + i*16 + lrow)*64 + ((kf2*4 + g) ^ sw)*8];
            for (int mi = 0; mi < 4; ++mi)
                for (int ni = 0; ni < 4; ++ni)
                    acc[mi][ni] = __builtin_amdgcn_mfma_f32_16x16x32_f16(a[mi], bf[ni], acc[mi][ni], 0, 0, 0);
        }
        __syncthreads();
    }

    const int rbase = g * 4;
    if (mode == 2) {
        for (int ni = 0; ni < 4; ++ni) {
            int n = n0 + wn + ni * 16 + lrow;
            float bval = bias[n];
            int hh = n >> 6, dep = n & 63;
            for (int mi = 0; mi < 4; ++mi) {
                int m = m0 + wm + mi * 16 + rbase;
                int bb = m >> 11, s = m & 2047;
                f16x4 pk = {(f16)(acc[mi][ni][0] + bval), (f16)(acc[mi][ni][1] + bval),
                            (f16)(acc[mi][ni][2] + bval), (f16)(acc[mi][ni][3] + bval)};
                *(f16x4*)&vt[((size_t)(bb * HH + hh) * DEPTH + dep) * SS + s] = pk;
            }
        }
    } else {
        f16* dst = (mode == 0) ? qh : kh;
        const float osc = (mode == 0) ? SC2 : 1.0f;   // fold logit scale into Q
        for (int ni = 0; ni < 4; ++ni) {
            int n = n0 + wn + ni * 16 + lrow;
            float bval = bias[n];
            int hh = n >> 6, dep = n & 63;
            for (int mi = 0; mi < 4; ++mi)
                for (int j = 0; j < 4; ++j) {
                    int m = m0 + wm + mi * 16 + rbase + j;
                    int bb = m >> 11, s = m & 2047;
                    dst[((size_t)(bb * HH + hh) * SS + s) * DEPTH + dep] =
                        (f16)((acc[mi][ni][j] + bval) * osc);
                }
        }
    }
}

// ---------------- Attention ----------------
// r13 counted-vmcnt structure + VALU diet: logits arrive pre-scaled (Q folded
// SC2), mask applied as MFMA C-operand init (f32 -1e9 bias, absorbs the +-2
// logit; exp2 underflows to exact 0 for masked keys).
__global__ __launch_bounds__(512, 4) void attn_kernel(
    const f16* __restrict__ qh, const f16* __restrict__ kh, const f16* __restrict__ vt,
    const float* __restrict__ mask, float* __restrict__ attn_out, f16* __restrict__ ctx)
{
    __shared__ float mlds[SS];            // mask bias (-1e9 or 0), 8KB
    __shared__ f16 Ks[3][64*64];          // K 3-buf (pass1: first 64 rows of 128-tile)
    __shared__ f16 Vs[3][64*64];          // V 3-buf (pass1: rows 64-127 of K-tile)
    __shared__ f16 Pl[QW][16][72];        // per-wave P bounce, 18KB

    const int tid = threadIdx.x, wave = tid >> 6, lane = tid & 63;
    const int L = blockIdx.x;             // 0..511; L&7 = XCD
    const int xcd = L & 7, iw = L >> 3;
    const int bh = xcd * 4 + (iw >> 4);   // 4 bh per XCD -> 2MB K/V per L2
    const int qb = iw & 15;
    const int b = bh >> 4, h = bh & 15;
    const int q0 = qb * QBLK;
    const int lrow = lane & 15, g = lane >> 4;
    const int rbase = g * 4;
    const int sw = lrow & 7;
    const int srow = tid >> 3;
    const int schk = (tid & 7) ^ (srow & 7);

    const f16* Qbase = qh + (size_t)bh * SS * DEPTH;
    const f16* Kb = kh + (size_t)bh * SS * DEPTH;
    const f16* Vb = vt + (size_t)bh * DEPTH * SS;

    for (int i = tid; i < SS; i += 512)
        mlds[i] = mask[b * SS + i] * -1e9f;

    f16x8 aq[2];
    for (int kf2 = 0; kf2 < 2; ++kf2)
        aq[kf2] = *(const f16x8*)(Qbase + (size_t)(q0 + wave*16 + lrow) * DEPTH + kf2*32 + g*8);

    // ---- pass 1: row sums of exp2(logit+maskbias), 128-row K tiles, 2-deep prefetch ----
    float s_l[4] = {0.f, 0.f, 0.f, 0.f};
    GLOAD16(Kb + (size_t)(srow) * DEPTH + schk * 8,        &Ks[0][wave * 512]);
    GLOAD16(Kb + (size_t)(64 + srow) * DEPTH + schk * 8,   &Vs[0][wave * 512]);
    GLOAD16(Kb + (size_t)(128 + srow) * DEPTH + schk * 8,  &Ks[1][wave * 512]);
    GLOAD16(Kb + (size_t)(192 + srow) * DEPTH + schk * 8,  &Vs[1][wave * 512]);
    __syncthreads();
    for (int t = 0; t < NT2; ++t) {
        const int cur = t % 3;
        const int nxt = (t + 2) % 3;
        const int t2 = (t + 2) & (NT2 - 1);   // wraparound keeps FIFO uniform
        GLOAD16(Kb + (size_t)(t2*128 + srow) * DEPTH + schk * 8,      &Ks[nxt][wave * 512]);
        GLOAD16(Kb + (size_t)(t2*128 + 64 + srow) * DEPTH + schk * 8, &Vs[nxt][wave * 512]);
        #pragma unroll
        for (int nf = 0; nf < 8; ++nf) {
            const f16* tb = (nf < 4) ? &Ks[cur][0] : &Vs[cur][0];
            const int nfl = nf & 3;
            float mb = mlds[t*128 + nf*16 + lrow];     // all 4 j share k=...+lrow
            f32x4 a4 = {mb, mb, mb, mb};               // mask as C-operand init
            for (int kf2 = 0; kf2 < 2; ++kf2) {
                f16x8 bf = *(const f16x8*)&tb[(nfl*16 + lrow)*64 + ((kf2*4 + g) ^ sw)*8];
                a4 = __builtin_amdgcn_mfma_f32_16x16x32_f16(aq[kf2], bf, a4, 0, 0, 0);
            }
            for (int j = 0; j < 4; ++j)
                s_l[j] += __builtin_amdgcn_exp2f(a4[j]);
        }
        if (t < NT2 - 1) BARV(2);
        else __syncthreads();   // full drain before pass-2 prologue reuses buffers
    }
    for (int j = 0; j < 4; ++j) {
        float s = s_l[j];
        for (int off = 1; off < 16; off <<= 1) s += __shfl_xor(s, off);
        s_l[j] = 1.0f / s;
    }

    // ---- pass 2: 2-deep prefetch, vmcnt(6) barriers, deferred NT stores ----
    f32x4 cacc[4] = {};
    f32x4 st[4];                           // deferred attn store regs (tile kt-1)
    float* arow = attn_out + ((size_t)bh * SS + q0 + wave * 16) * SS;
    GLOAD16(Kb + (size_t)(srow) * DEPTH + schk * 8,        &Ks[0][wave * 512]);
    GLOAD16(Vb + (size_t)srow * SS + 0 + schk * 8,         &Vs[0][wave * 512]);
    GLOAD16(Kb + (size_t)(64 + srow) * DEPTH + schk * 8,   &Ks[1][wave * 512]);
    GLOAD16(Vb + (size_t)srow * SS + 64 + schk * 8,        &Vs[1][wave * 512]);
    __syncthreads();
    for (int kt = 0; kt < NT; ++kt) {
        const int cur = kt % 3;
        const int nxt = (kt + 2) % 3;
        const int t2 = (kt + 2) & (NT - 1);
        // previous tile's stores first (a full iteration of ack slack)
        if (kt > 0) {
            #pragma unroll
            for (int i = 0; i < 4; ++i) {
                int r = i * 4 + g;
                __builtin_nontemporal_store(st[i],
                    (f32x4*)&arow[(size_t)r * SS + (kt-1)*64 + lrow*4]);
            }
        }
        GLOAD16(Kb + (size_t)(t2*64 + srow) * DEPTH + schk * 8, &Ks[nxt][wave * 512]);
        GLOAD16(Vb + (size_t)srow * SS + t2*64 + schk * 8,      &Vs[nxt][wave * 512]);
        // QK^T (mask via C-init) + normalized P -> Pl
        for (int nf = 0; nf < 4; ++nf) {
            float mb = mlds[kt*64 + nf*16 + lrow];
            f32x4 a4 = {mb, mb, mb, mb};
            for (int kf2 = 0; kf2 < 2; ++kf2) {
                f16x8 bf = *(const f16x8*)&Ks[cur][(nf*16 + lrow)*64 + ((kf2*4 + g) ^ sw)*8];
                a4 = __builtin_amdgcn_mfma_f32_16x16x32_f16(aq[kf2], bf, a4, 0, 0, 0);
            }
            for (int j = 0; j < 4; ++j) {
                float p = __builtin_amdgcn_exp2f(a4[j]) * s_l[j];
                Pl[wave][rbase + j][nf*16 + lrow] = (f16)p;
            }
        }
        // PV: A = P (same-wave LDS bounce), B = V tile
        for (int kf2 = 0; kf2 < 2; ++kf2) {
            f16x8 pa = *(const f16x8*)&Pl[wave][lrow][kf2*32 + g*8];
            for (int nf = 0; nf < 4; ++nf) {
                f16x8 bv = *(const f16x8*)&Vs[cur][(nf*16 + lrow)*64 + ((kf2*4 + g) ^ sw)*8];
                cacc[nf] = __builtin_amdgcn_mfma_f32_16x16x32_f16(pa, bv, cacc[nf], 0, 0, 0);
            }
        }
        // read this tile's attn rows (transposed) into regs for deferred store
        #pragma unroll
        for (int i = 0; i < 4; ++i) {
            int r = i * 4 + g;
            f16x4 pv4 = *(const f16x4*)&Pl[wave][r][lrow * 4];
            st[i] = (f32x4){(float)pv4[0], (float)pv4[1], (float)pv4[2], (float)pv4[3]};
        }
        BARV(6);   // drains gloads(kt+1) exactly; stores(kt-1)+gloads(kt+2) stay
    }
    // final tile's stores
    #pragma unroll
    for (int i = 0; i < 4; ++i) {
        int r = i * 4 + g;
        __builtin_nontemporal_store(st[i],
            (f32x4*)&arow[(size_t)r * SS + (NT-1)*64 + lrow*4]);
    }
    // ctx [b, s, h, d] f16 for dense GEMM
    for (int nf = 0; nf < 4; ++nf)
        for (int j = 0; j < 4; ++j) {
            int qrow = q0 + wave * 16 + rbase + j;
            ctx[((size_t)(b * SS + qrow) * HH + h) * DEPTH + nf*16 + lrow] = (f16)cacc[nf][j];
        }
    ENDDRAIN();   // wraparound gloads must land before LDS is reallocated
}

// ---------------- Dense (f16 A/B, r12 verified form) ----------------
__global__ __launch_bounds__(256, 4) void dense_kernel(
    const f16* __restrict__ ctx, const f16* __restrict__ W16,
    const float* __restrict__ bias, float* __restrict__ out)
{
    __shared__ f16 As[128*64];
    __shared__ f16 Bs[128*64];

    const int tid = threadIdx.x, wave = tid >> 6, lane = tid & 63;
    const int m0 = blockIdx.y * 128, n0 = blockIdx.x * 128;
    const int wm = (wave >> 1) * 64, wn = (wave & 1) * 64;
    const int lrow = lane & 15, g = lane >> 4;
    const int sw = lrow & 7;
    const int srow = tid >> 3;
    const int schk = (tid & 7) ^ (srow & 7);

    f32x4 acc[4][4] = {};

    for (int kk = 0; kk < DD; kk += 64) {
        #pragma unroll
        for (int i = 0; i < 4; ++i) {
            GLOAD16(ctx + (size_t)(m0 + i*32 + srow) * DD + kk + schk * 8,
                    &As[i*2048 + wave*512]);
            GLOAD16(W16 + (size_t)(n0 + i*32 + srow) * DD + kk + schk * 8,
                    &Bs[i*2048 + wave*512]);
        }
        __syncthreads();
        for (int kf2 = 0; kf2 < 2; ++kf2) {
            f16x8 a[4], bf[4];
            for (int i = 0; i < 4; ++i)
                a[i]  = *(const f16x8*)&As[(wm + i*16 + lrow)*64 + ((kf2*4 + g) ^ sw)*8];
            for (int i = 0; i < 4; ++i)
                bf[i] = *(const f16x8*)&Bs[(wn + i*16 + lrow)*64 + ((kf2*4 + g) ^ sw)*8];
            for (int mi = 0; mi < 4; ++mi)
                for (int ni = 0; ni < 4; ++ni)
                    acc[mi][ni] = __builtin_amdgcn_mfma_f32_16x16x32_f16(a[mi], bf[ni], acc[mi][ni], 0, 0, 0);
        }
        __syncthreads();
    }

    const int rbase = g * 4;
    for (int ni = 0; ni < 4; ++ni) {
        int n = n0 + wn + ni * 16 + lrow;
        float bval = bias[n];
        for (int mi = 0; mi < 4; ++mi)
            for (int j = 0; j < 4; ++j) {
                int m = m0 + wm + mi * 16 + rbase + j;
                out[(size_t)m * DD + n] = acc[mi][ni][j] + bval;
            }
    }
}

extern "C" void kernel_launch(void* const* d_in, const int* in_sizes, int n_in,
                              void* d_out, int out_size, void* d_ws, size_t ws_size,
                              hipStream_t stream) {
    const float* q       = (const float*)d_in[0];
    const float* k       = (const float*)d_in[1];
    const float* v       = (const float*)d_in[2];
    const float* mask    = (const float*)d_in[3];
    const float* wq_w    = (const float*)d_in[4];
    const float* wq_b    = (const float*)d_in[5];
    const float* wk_w    = (const float*)d_in[6];
    const float* wk_b    = (const float*)d_in[7];
    const float* wv_w    = (const float*)d_in[8];
    const float* wv_b    = (const float*)d_in[9];
    const float* dense_w = (const float*)d_in[10];
    const float* dense_b = (const float*)d_in[11];

    float* out  = (float*)d_out;
    float* attn = out + (size_t)MTOT * DD;          // output-1 region (537MB)

    // ws: persistent intermediates (proven <= ws_size: 33.6MB)
    f16* qh  = (f16*)d_ws;
    f16* kh  = qh + NPROJ;
    f16* vt  = kh + NPROJ;
    f16* ctx = vt + NPROJ;

    // Transient f16 copies in the attn OUTPUT region (dead after proj; attn
    // pass 2 overwrites the whole region afterwards, stream-ordered).
    f16* sc   = (f16*)attn;
    f16* qf   = sc;
    f16* kf   = sc + NPROJ;
    f16* vf   = sc + 2*NPROJ;
    f16* wq16 = sc + 3*NPROJ;
    f16* wk16 = wq16 + WSZ;
    f16* wv16 = wk16 + WSZ;

    // dense_w f16 copy lives in the qh region (dead after attn completes).
    f16* dw16 = qh;

    cvt_kernel<<<dim3(1024, 6), 256, 0, stream>>>(q, k, v, wq_w, wk_w, wv_w,
                                                  qf, kf, vf, wq16, wk16, wv16);
    proj_kernel<<<dim3(8, 32, 3), 256, 0, stream>>>(qf, kf, vf, wq16, wk16, wv16,
                                                    wq_b, wk_b, wv_b, qh, kh, vt);
    attn_kernel<<<dim3(512), 512, 0, stream>>>(qh, kh, vt, mask, attn, ctx);
    cvt2_kernel<<<dim3(512), 256, 0, stream>>>(dense_w, dw16);
    dense_kernel<<<dim3(8, 32), 256, 0, stream>>>(ctx, dw16, dense_b, out);
}